// Round 1
// baseline (1217.906 us; speedup 1.0000x reference)
//
#include <hip/hip_runtime.h>

#define NN 100000
#define NE 1600000
#define NB_SCAN 391   // ceil(NN/256)

// ---------------- CSR build ----------------

__global__ void count_kernel(const int* __restrict__ dst, int* __restrict__ counts) {
  int i = blockIdx.x * blockDim.x + threadIdx.x;
  int st = gridDim.x * blockDim.x;
  for (; i < NE; i += st) atomicAdd(&counts[dst[i]], 1);
}

__global__ void dinv_kernel(const int* __restrict__ counts, float* __restrict__ dinv,
                            float* __restrict__ selfinv) {
  int i = blockIdx.x * blockDim.x + threadIdx.x;
  if (i < NN) {
    float deg = (float)counts[i] + 1.0f;
    dinv[i] = rsqrtf(deg);
    selfinv[i] = 1.0f / deg;
  }
}

__global__ void scan1_kernel(const int* __restrict__ counts, int* __restrict__ offsets,
                             int* __restrict__ blocksum) {
  __shared__ int s[256];
  int t = threadIdx.x;
  int i = blockIdx.x * 256 + t;
  int v = (i < NN) ? counts[i] : 0;
  s[t] = v; __syncthreads();
  for (int off = 1; off < 256; off <<= 1) {
    int x = 0;
    if (t >= off) x = s[t - off];
    __syncthreads();
    if (t >= off) s[t] += x;
    __syncthreads();
  }
  if (i < NN) offsets[i] = s[t] - v;          // exclusive within block
  if (t == 255) blocksum[blockIdx.x] = s[255];
}

__global__ void scan2_kernel(const int* __restrict__ blocksum, int* __restrict__ blockpfx,
                             int* __restrict__ offsets) {
  __shared__ int s[512];
  int t = threadIdx.x;
  int v = (t < NB_SCAN) ? blocksum[t] : 0;
  s[t] = v; __syncthreads();
  for (int off = 1; off < 512; off <<= 1) {
    int x = 0;
    if (t >= off) x = s[t - off];
    __syncthreads();
    if (t >= off) s[t] += x;
    __syncthreads();
  }
  if (t < NB_SCAN) blockpfx[t] = s[t] - v;
  if (t == 511) offsets[NN] = s[511];         // == NE
}

__global__ void scan3_kernel(int* __restrict__ offsets, const int* __restrict__ blockpfx,
                             int* __restrict__ cursor) {
  int i = blockIdx.x * 256 + threadIdx.x;
  if (i < NN) {
    int v = offsets[i] + blockpfx[i >> 8];
    offsets[i] = v;
    cursor[i] = v;
  }
}

__global__ void scatter_kernel(const int* __restrict__ src, const int* __restrict__ dst,
                               const float* __restrict__ dinv, int* __restrict__ cursor,
                               int* __restrict__ src_s, float* __restrict__ norm_s) {
  int i = blockIdx.x * blockDim.x + threadIdx.x;
  int st = gridDim.x * blockDim.x;
  for (; i < NE; i += st) {
    int s = src[i], d = dst[i];
    int pos = atomicAdd(&cursor[d], 1);
    src_s[pos] = s;
    norm_s[pos] = dinv[s] * dinv[d];
  }
}

// ---------------- GEMM 64x64 with fused BN-apply+ReLU on input ----------------
// block = 256 threads (4 waves), 16 rows per block, each thread does 4 rows x 1 col.

__global__ __launch_bounds__(256) void gemm64_kernel(
    const float* __restrict__ x, const float* __restrict__ W, const float* __restrict__ bias,
    const float* __restrict__ gamma, const float* __restrict__ beta,
    const float* __restrict__ meanistd, int relu_in, float* __restrict__ out) {
  __shared__ float sW[64][64];
  __shared__ float sx[16][64];
  int t = threadIdx.x;
  int col = t & 63;
  int row0 = blockIdx.x * 16;

#pragma unroll
  for (int j = 0; j < 16; ++j) {
    int e = t + 256 * j;              // e & 63 == col
    sW[e >> 6][col] = W[e];
  }
  float g = 1.f, bt = 0.f, mn = 0.f, is = 1.f;
  if (gamma) { g = gamma[col]; bt = beta[col]; mn = meanistd[col]; is = meanistd[64 + col]; }
#pragma unroll
  for (int j = 0; j < 4; ++j) {
    int e = t + 256 * j;
    int r = e >> 6;                   // 0..15
    int grow = row0 + r;
    float v = 0.f;
    if (grow < NN) v = x[(size_t)grow * 64 + col];
    if (gamma) { v = g * (v - mn) * is + bt; if (relu_in) v = fmaxf(v, 0.f); }
    sx[r][col] = v;
  }
  __syncthreads();

  int wave = t >> 6;
  float acc0 = 0, acc1 = 0, acc2 = 0, acc3 = 0;
#pragma unroll
  for (int k = 0; k < 64; ++k) {
    float wv = sW[k][col];
    acc0 += sx[wave * 4 + 0][k] * wv;
    acc1 += sx[wave * 4 + 1][k] * wv;
    acc2 += sx[wave * 4 + 2][k] * wv;
    acc3 += sx[wave * 4 + 3][k] * wv;
  }
  float bv = bias ? bias[col] : 0.f;
  int r0 = row0 + wave * 4;
  if (r0 + 0 < NN) out[(size_t)(r0 + 0) * 64 + col] = acc0 + bv;
  if (r0 + 1 < NN) out[(size_t)(r0 + 1) * 64 + col] = acc1 + bv;
  if (r0 + 2 < NN) out[(size_t)(r0 + 2) * 64 + col] = acc2 + bv;
  if (r0 + 3 < NN) out[(size_t)(r0 + 3) * 64 + col] = acc3 + bv;
}

// ---------------- Edge aggregation + self loop + bias + BN stats ----------------
// one wave per node (lane = channel), grid-stride; per-block partial stats -> 2 atomics/ch.

__global__ __launch_bounds__(256) void agg_kernel(
    const float* __restrict__ h, const int* __restrict__ offsets,
    const int* __restrict__ src_s, const float* __restrict__ norm_s,
    const float* __restrict__ selfinv, const float* __restrict__ bvec,
    float* __restrict__ h2, float* __restrict__ bnacc) {
  int lane = threadIdx.x & 63;
  int wv = threadIdx.x >> 6;
  int gw = blockIdx.x * 4 + wv;
  int nw = gridDim.x * 4;
  float bias = bvec[lane];
  float s1 = 0.f, s2 = 0.f;
  for (int n = gw; n < NN; n += nw) {
    int beg = offsets[n], end = offsets[n + 1];
    float acc = selfinv[n] * h[(size_t)n * 64 + lane];
    for (int j = beg; j < end; ++j) {
      int sidx = src_s[j];
      float w = norm_s[j];
      acc += w * h[(size_t)sidx * 64 + lane];
    }
    float v = acc + bias;
    h2[(size_t)n * 64 + lane] = v;
    s1 += v;
    s2 += v * v;
  }
  __shared__ float ls[4][2][64];
  ls[wv][0][lane] = s1;
  ls[wv][1][lane] = s2;
  __syncthreads();
  if (wv == 0) {
    float a = ls[0][0][lane] + ls[1][0][lane] + ls[2][0][lane] + ls[3][0][lane];
    float b = ls[0][1][lane] + ls[1][1][lane] + ls[2][1][lane] + ls[3][1][lane];
    atomicAdd(&bnacc[lane], a);
    atomicAdd(&bnacc[64 + lane], b);
  }
}

__global__ void bn_finalize_kernel(const float* __restrict__ bnacc, float* __restrict__ bnpar) {
  int c = threadIdx.x;  // 64 threads
  float mean = bnacc[c] * (1.0f / NN);
  float var = bnacc[64 + c] * (1.0f / NN) - mean * mean;
  bnpar[c] = mean;
  bnpar[64 + c] = rsqrtf(var + 1e-5f);
}

// ---------------- Output MLP: BN-apply -> Linear(64,128)+ReLU -> Linear(128,1) ----------------
// one wave per row, W1 staged in LDS (32KB), x broadcast via shuffles.

__global__ __launch_bounds__(256) void out_kernel(
    const float* __restrict__ x,
    const float* __restrict__ gamma, const float* __restrict__ beta,
    const float* __restrict__ meanistd,
    const float* __restrict__ W1, const float* __restrict__ b1,
    const float* __restrict__ W2, const float* __restrict__ b2,
    float* __restrict__ out) {
  __shared__ float sW1[64][128];
  __shared__ float sW2[128];
  int t = threadIdx.x;
#pragma unroll
  for (int j = 0; j < 32; ++j) {
    int e = t + 256 * j;
    sW1[e >> 7][e & 127] = W1[e];
  }
  if (t < 128) sW2[t] = W2[t];
  __syncthreads();

  int lane = t & 63, wv = t >> 6;
  float g = gamma[lane], bt = beta[lane], mn = meanistd[lane], is = meanistd[64 + lane];
  float b1a = b1[lane], b1b = b1[64 + lane];
  float w2a = sW2[lane], w2b = sW2[64 + lane];
  float bias2 = b2[0];
  int nw = gridDim.x * 4;
  for (int row = blockIdx.x * 4 + wv; row < NN; row += nw) {
    float xv = x[(size_t)row * 64 + lane];
    xv = g * (xv - mn) * is + bt;   // last-layer BN, no ReLU
    float acc0 = 0, acc1 = 0;
#pragma unroll
    for (int k = 0; k < 64; ++k) {
      float xk = __shfl(xv, k);
      acc0 += xk * sW1[k][lane];
      acc1 += xk * sW1[k][64 + lane];
    }
    acc0 = fmaxf(acc0 + b1a, 0.f);
    acc1 = fmaxf(acc1 + b1b, 0.f);
    float p = acc0 * w2a + acc1 * w2b;
#pragma unroll
    for (int off = 32; off > 0; off >>= 1) p += __shfl_down(p, off);
    if (lane == 0) out[row] = p + bias2;
  }
}

// ---------------- launch ----------------

extern "C" void kernel_launch(void* const* d_in, const int* in_sizes, int n_in,
                              void* d_out, int out_size, void* d_ws, size_t ws_size,
                              hipStream_t stream) {
  const float* X = (const float*)d_in[0];
  const int* edge = (const int*)d_in[1];
  const int* esrc = edge;
  const int* edst = edge + NE;
  const float* W_in = (const float*)d_in[2];
  const float* b_in = (const float*)d_in[3];
  const float* Ws = (const float*)d_in[4];
  const float* bs = (const float*)d_in[5];
  const float* gammas = (const float*)d_in[6];
  const float* betas = (const float*)d_in[7];
  const float* W1 = (const float*)d_in[8];
  const float* b1 = (const float*)d_in[9];
  const float* W2 = (const float*)d_in[10];
  const float* b2 = (const float*)d_in[11];
  float* out = (float*)d_out;

  char* base = (char*)d_ws;
  size_t o = 0;
  auto alloc = [&](size_t bytes) {
    o = (o + 255) & ~(size_t)255;
    void* p = base + o;
    o += bytes;
    return p;
  };
  int* counts = (int*)alloc((size_t)NN * 4);
  int* offsets = (int*)alloc((size_t)(NN + 1) * 4);
  int* cursor = (int*)alloc((size_t)NN * 4);
  int* blocksum = (int*)alloc(512 * 4);
  int* blockpfx = (int*)alloc(512 * 4);
  int* src_s = (int*)alloc((size_t)NE * 4);
  float* norm_s = (float*)alloc((size_t)NE * 4);
  float* dinv = (float*)alloc((size_t)NN * 4);
  float* selfinv = (float*)alloc((size_t)NN * 4);
  float* bufA = (float*)alloc((size_t)NN * 64 * 4);
  float* bufB = (float*)alloc((size_t)NN * 64 * 4);
  float* hbuf = (float*)alloc((size_t)NN * 64 * 4);
  float* bnacc = (float*)alloc(3 * 128 * 4);
  float* bnpar = (float*)alloc(3 * 128 * 4);

  hipMemsetAsync(counts, 0, (size_t)NN * 4, stream);
  hipMemsetAsync(bnacc, 0, 3 * 128 * 4, stream);

  count_kernel<<<2048, 256, 0, stream>>>(edst, counts);
  dinv_kernel<<<(NN + 255) / 256, 256, 0, stream>>>(counts, dinv, selfinv);
  scan1_kernel<<<NB_SCAN, 256, 0, stream>>>(counts, offsets, blocksum);
  scan2_kernel<<<1, 512, 0, stream>>>(blocksum, blockpfx, offsets);
  scan3_kernel<<<NB_SCAN, 256, 0, stream>>>(offsets, blockpfx, cursor);
  scatter_kernel<<<2048, 256, 0, stream>>>(esrc, edst, dinv, cursor, src_s, norm_s);

  const int GEMM_GRID = (NN + 15) / 16;
  // input Linear: x = X @ W_in + b_in
  gemm64_kernel<<<GEMM_GRID, 256, 0, stream>>>(X, W_in, b_in, nullptr, nullptr, nullptr, 0, bufA);

  const float* xcur = bufA;
  float* xnext = bufB;
  for (int i = 0; i < 3; ++i) {
    const float* g  = (i == 0) ? nullptr : gammas + (size_t)(i - 1) * 64;
    const float* bt = (i == 0) ? nullptr : betas + (size_t)(i - 1) * 64;
    const float* mi = (i == 0) ? nullptr : bnpar + (size_t)(i - 1) * 128;
    gemm64_kernel<<<GEMM_GRID, 256, 0, stream>>>(xcur, Ws + (size_t)i * 64 * 64, nullptr,
                                                 g, bt, mi, 1, hbuf);
    agg_kernel<<<2048, 256, 0, stream>>>(hbuf, offsets, src_s, norm_s, selfinv,
                                         bs + (size_t)i * 64, xnext, bnacc + (size_t)i * 128);
    bn_finalize_kernel<<<1, 64, 0, stream>>>(bnacc + (size_t)i * 128, bnpar + (size_t)i * 128);
    const float* tmp = xcur;
    xcur = xnext;
    xnext = (float*)tmp;
  }
  // after loop: xcur holds layer-2 pre-BN output
  out_kernel<<<2048, 256, 0, stream>>>(xcur, gammas + 2 * 64, betas + 2 * 64, bnpar + 2 * 128,
                                       W1, b1, W2, b2, out);
}